// Round 4
// baseline (527.659 us; speedup 1.0000x reference)
//
#include <hip/hip_runtime.h>
#include <math.h>

#define EMBED 1024
#define HIDDEN 4096
#define ROWS_CAP 3072

// workspace layout (bytes)
#define WS_COUNT   0
#define WS_BASE    64
#define WS_TIDX    4096
#define WS_TW      12288
#define WS_ROWTOK  20480
#define WS_ROWW    32768
#define WS_H       65536ULL

typedef short short8 __attribute__((ext_vector_type(8)));
typedef float f32x4 __attribute__((ext_vector_type(4)));

__device__ __forceinline__ short f2bf(float f) {
  __bf16 h = (__bf16)f;
  return __builtin_bit_cast(short, h);
}

__device__ __forceinline__ short8 pack8(float4 a, float4 b) {
  short8 r;
  r[0] = f2bf(a.x); r[1] = f2bf(a.y); r[2] = f2bf(a.z); r[3] = f2bf(a.w);
  r[4] = f2bf(b.x); r[5] = f2bf(b.y); r[6] = f2bf(b.z); r[7] = f2bf(b.w);
  return r;
}

// raw barrier + lgkm-only drain: ds_writes visible at the barrier; global loads
// (vmcnt) deliberately left in flight across it. The compiler emits the exact
// counted vmcnt before the pack/ds_write uses of each stage's registers.
#define LGKM0() asm volatile("s_waitcnt lgkmcnt(0)" ::: "memory")
#define SBAR()  asm volatile("s_barrier" ::: "memory")

// ---------------- router ----------------
__global__ __launch_bounds__(256) void router_kernel(
    const float* __restrict__ x, const float* __restrict__ gw,
    int* __restrict__ count, int2* __restrict__ t_idx, float2* __restrict__ t_w) {
  int t = blockIdx.x * 4 + (threadIdx.x >> 6);
  int lane = threadIdx.x & 63;
  const float* xr = x + (size_t)t * EMBED;
  float acc[8] = {0.f,0.f,0.f,0.f,0.f,0.f,0.f,0.f};
#pragma unroll
  for (int c = 0; c < 4; ++c) {
    float4 xv = *(const float4*)(xr + lane * 4 + c * 256);
#pragma unroll
    for (int e = 0; e < 8; ++e) {
      float4 gv = *(const float4*)(gw + e * EMBED + lane * 4 + c * 256);
      acc[e] += xv.x * gv.x + xv.y * gv.y + xv.z * gv.z + xv.w * gv.w;
    }
  }
#pragma unroll
  for (int e = 0; e < 8; ++e) {
#pragma unroll
    for (int off = 32; off > 0; off >>= 1) acc[e] += __shfl_down(acc[e], off);
  }
  if (lane == 0) {
    float m = acc[0];
#pragma unroll
    for (int e = 1; e < 8; ++e) m = fmaxf(m, acc[e]);
    float p[8]; float s = 0.f;
#pragma unroll
    for (int e = 0; e < 8; ++e) { p[e] = expf(acc[e] - m); s += p[e]; }
    float inv = 1.0f / s;
#pragma unroll
    for (int e = 0; e < 8; ++e) p[e] *= inv;
    int i0 = 0; float p0 = p[0];
#pragma unroll
    for (int e = 1; e < 8; ++e) if (p[e] > p0) { p0 = p[e]; i0 = e; }
    int i1 = -1; float p1 = -1.f;
#pragma unroll
    for (int e = 0; e < 8; ++e) if (e != i0 && p[e] > p1) { p1 = p[e]; i1 = e; }
    float denom = p0 + p1 + 1e-9f;
    atomicAdd(&count[i0], 1);
    atomicAdd(&count[i1], 1);
    t_idx[t] = make_int2(i0, i1);
    t_w[t] = make_float2(p0 / denom, p1 / denom);
  }
}

// ---------------- assign ----------------
__global__ __launch_bounds__(256) void assign_kernel(
    const int* __restrict__ count, int* __restrict__ base,
    const int2* __restrict__ t_idx, const float2* __restrict__ t_w,
    int* __restrict__ row_token, float* __restrict__ row_w, int T) {
  __shared__ int s_base[8];
  __shared__ int s_cur[8];
  int tid = threadIdx.x;
  for (int i = tid; i < ROWS_CAP; i += 256) row_token[i] = -1;
  if (tid == 0) {
    int b = 0;
    for (int e = 0; e < 8; ++e) {
      s_base[e] = b; base[e] = b;
      b += (count[e] + 127) & ~127;
    }
  }
  if (tid < 8) s_cur[tid] = 0;
  __syncthreads();
  for (int t = tid; t < T; t += 256) {
    int2 ii = t_idx[t]; float2 ww = t_w[t];
    int p = atomicAdd(&s_cur[ii.x], 1);
    int r = s_base[ii.x] + p;
    row_token[r] = t; row_w[r] = ww.x;
    p = atomicAdd(&s_cur[ii.y], 1);
    r = s_base[ii.y] + p;
    row_token[r] = t; row_w[r] = ww.y;
  }
}

// ======== FFN1/FFN2: reg-staged pipeline with fused fp32->bf16 conversion ======
// No weight repack pass: B is read straight from fp32 [k][n] weights with 8
// k-strided dword loads per LDS slot (coalesced across lanes: consecutive
// threads hold consecutive n). Conversion happens in-register at ds_write time.
// LDS image identical to R3 (rows [128] x k[32] bf16, tid-contiguous writes).

#define STG_COMP(buf) do { \
    const short* Af_ = &As[buf][aoff]; \
    const short* Bf_ = &Bs[buf][boff]; \
    short8 a_[4], bb_[4]; \
    _Pragma("unroll") \
    for (int i = 0; i < 4; ++i) a_[i]  = *(const short8*)(Af_ + i * 512); \
    _Pragma("unroll") \
    for (int j = 0; j < 4; ++j) bb_[j] = *(const short8*)(Bf_ + j * 512); \
    __builtin_amdgcn_s_setprio(1); \
    _Pragma("unroll") \
    for (int i = 0; i < 4; ++i) { \
      _Pragma("unroll") \
      for (int j = 0; j < 4; ++j) \
        acc[i][j] = __builtin_amdgcn_mfma_f32_16x16x32_bf16(a_[i], bb_[j], acc[i][j], 0, 0, 0); \
    } \
    __builtin_amdgcn_s_setprio(0); \
  } while (0)

// ---------------- FFN1: H = gelu(X @ W1 + b1), X fp32, W1 fp32 [k][n] ----------
// grid (32, 64): x = n-tile (128 over HIDDEN), y = e*8 + mt (128-row tiles)
__global__ __launch_bounds__(256) void ffn1_kernel(
    const float* __restrict__ x, const float* __restrict__ w1,
    const float* __restrict__ b1, const int* __restrict__ count,
    const int* __restrict__ base, const int* __restrict__ row_token,
    unsigned short* __restrict__ H) {
  int nt = blockIdx.x;
  int e  = blockIdx.y >> 3;
  int mt = blockIdx.y & 7;
  int cnt = count[e];
  if (mt * 128 >= cnt) return;
  int base_e = base[e];
  int n0 = nt * 128;

  __shared__ __align__(16) short As[2][4096];
  __shared__ __align__(16) short Bs[2][4096];

  int tid = threadIdx.x, wv = tid >> 6, lane = tid & 63;

  // A slots: flat in {tid, 256+tid}; row = flat>>2, kq = flat&3.
  int row0 = tid >> 2, row1 = 64 + row0, kq = tid & 3;
  int pos0 = mt * 128 + row0;
  int tok0 = (pos0 < cnt) ? row_token[base_e + pos0] : 0;
  if (tok0 < 0) tok0 = 0;
  int pos1 = mt * 128 + row1;
  int tok1 = (pos1 < cnt) ? row_token[base_e + pos1] : 0;
  if (tok1 < 0) tok1 = 0;
  const float* aptr0 = x + (size_t)tok0 * EMBED + kq * 8;
  const float* aptr1 = x + (size_t)tok1 * EMBED + kq * 8;
  // B slots: n = flat>>2 (0..127), kq = flat&3; reads w1[(kc*32+kq*8+j)][n0+n].
  const float* bptr0 = w1 + (size_t)e * EMBED * HIDDEN
                          + (size_t)kq * 8 * HIDDEN + n0 + row0;

  int wm = wv & 1, wn = wv >> 1;
  int quad = lane >> 4, l15 = lane & 15;
  int aoff = (wm * 64 + l15) * 32 + quad * 8;
  int boff = (wn * 64 + l15) * 32 + quad * 8;

  f32x4 acc[4][4];
#pragma unroll
  for (int i = 0; i < 4; ++i)
#pragma unroll
    for (int j = 0; j < 4; ++j) acc[i][j] = (f32x4){0.f, 0.f, 0.f, 0.f};

#define F1_LOAD(kc, A0, A1, A2, A3, B) do { \
    const float* ap0_ = aptr0 + (kc) * 32; \
    const float* ap1_ = aptr1 + (kc) * 32; \
    A0 = *(const float4*)(ap0_);     A1 = *(const float4*)(ap0_ + 4); \
    A2 = *(const float4*)(ap1_);     A3 = *(const float4*)(ap1_ + 4); \
    const float* bp_ = bptr0 + (size_t)(kc) * 32 * HIDDEN; \
    _Pragma("unroll") \
    for (int j_ = 0; j_ < 8; ++j_) B[j_]     = bp_[(size_t)j_ * HIDDEN]; \
    _Pragma("unroll") \
    for (int j_ = 0; j_ < 8; ++j_) B[8 + j_] = bp_[(size_t)j_ * HIDDEN + 64]; \
  } while (0)

#define F1_DSW(buf, A0, A1, A2, A3, B) do { \
    short8 pa0_ = pack8(A0, A1); \
    short8 pa1_ = pack8(A2, A3); \
    short8 pb0_, pb1_; \
    _Pragma("unroll") \
    for (int j_ = 0; j_ < 8; ++j_) { pb0_[j_] = f2bf(B[j_]); pb1_[j_] = f2bf(B[8 + j_]); } \
    *(short8*)(&As[buf][tid * 8])        = pa0_; \
    *(short8*)(&As[buf][2048 + tid * 8]) = pa1_; \
    *(short8*)(&Bs[buf][tid * 8])        = pb0_; \
    *(short8*)(&Bs[buf][2048 + tid * 8]) = pb1_; \
  } while (0)

  {
    float4 a00, a01, a02, a03, a10, a11, a12, a13;
    float rb0[16], rb1[16];
    F1_LOAD(0, a00, a01, a02, a03, rb0);
    F1_DSW(0, a00, a01, a02, a03, rb0);
    F1_LOAD(1, a10, a11, a12, a13, rb1);
    LGKM0(); SBAR();
    for (int kc = 0; kc < 30; kc += 2) {
      F1_LOAD(kc + 2, a00, a01, a02, a03, rb0);
      STG_COMP(0);
      F1_DSW(1, a10, a11, a12, a13, rb1);
      LGKM0(); SBAR();
      F1_LOAD(kc + 3, a10, a11, a12, a13, rb1);
      STG_COMP(1);
      F1_DSW(0, a00, a01, a02, a03, rb0);
      LGKM0(); SBAR();
    }
    STG_COMP(0);
    F1_DSW(1, a10, a11, a12, a13, rb1);
    LGKM0(); SBAR();
    STG_COMP(1);
  }

  const float* b1e = b1 + e * HIDDEN;
#pragma unroll
  for (int i = 0; i < 4; ++i) {
    int rl = wm * 64 + i * 16 + quad * 4;
#pragma unroll
    for (int rg = 0; rg < 4; ++rg) {
      int pos = mt * 128 + rl + rg;
      if (pos < cnt) {
        unsigned short* hrow = H + (size_t)(base_e + pos) * HIDDEN;
#pragma unroll
        for (int j = 0; j < 4; ++j) {
          int col = n0 + wn * 64 + j * 16 + l15;
          float v = acc[i][j][rg] + b1e[col];
          float g = 0.5f * v * (1.0f + erff(v * 0.70710678118654752f));
          hrow[col] = (unsigned short)f2bf(g);
        }
      }
    }
  }
}

// ---------------- FFN2: out += w_r * (H @ W2 + b2), H bf16, W2 fp32 [k][n] -----
// grid (8, 64, 4): x = n-tile (128 over EMBED), y = e*8 + mt, z = K split (1024)
__global__ __launch_bounds__(256) void ffn2_kernel(
    const unsigned short* __restrict__ H, const float* __restrict__ w2,
    const float* __restrict__ b2, const int* __restrict__ count,
    const int* __restrict__ base, const int* __restrict__ row_token,
    const float* __restrict__ row_w, float* __restrict__ out) {
  int nt = blockIdx.x;
  int e  = blockIdx.y >> 3;
  int mt = blockIdx.y & 7;
  int sp = blockIdx.z;
  int cnt = count[e];
  if (mt * 128 >= cnt) return;
  int base_e = base[e];
  int n0 = nt * 128;

  __shared__ __align__(16) short As[2][4096];
  __shared__ __align__(16) short Bs[2][4096];

  int tid = threadIdx.x, wv = tid >> 6, lane = tid & 63;

  int row0 = tid >> 2, kq = tid & 3;
  const unsigned short* aptr0 =
      H + (size_t)(base_e + mt * 128 + row0) * HIDDEN + sp * 1024 + kq * 8;
  const unsigned short* aptr1 =
      H + (size_t)(base_e + mt * 128 + 64 + row0) * HIDDEN + sp * 1024 + kq * 8;
  const float* bptr0 = w2 + (size_t)e * HIDDEN * EMBED
                          + ((size_t)sp * 1024 + (size_t)kq * 8) * EMBED + n0 + row0;

  int wm = wv & 1, wn = wv >> 1;
  int quad = lane >> 4, l15 = lane & 15;
  int aoff = (wm * 64 + l15) * 32 + quad * 8;
  int boff = (wn * 64 + l15) * 32 + quad * 8;

  f32x4 acc[4][4];
#pragma unroll
  for (int i = 0; i < 4; ++i)
#pragma unroll
    for (int j = 0; j < 4; ++j) acc[i][j] = (f32x4){0.f, 0.f, 0.f, 0.f};

#define F2_LOAD(kc, A0, A1, B) do { \
    A0 = *(const short8*)(aptr0 + (kc) * 32); \
    A1 = *(const short8*)(aptr1 + (kc) * 32); \
    const float* bp_ = bptr0 + (size_t)(kc) * 32 * EMBED; \
    _Pragma("unroll") \
    for (int j_ = 0; j_ < 8; ++j_) B[j_]     = bp_[(size_t)j_ * EMBED]; \
    _Pragma("unroll") \
    for (int j_ = 0; j_ < 8; ++j_) B[8 + j_] = bp_[(size_t)j_ * EMBED + 64]; \
  } while (0)

#define F2_DSW(buf, A0, A1, B) do { \
    short8 pb0_, pb1_; \
    _Pragma("unroll") \
    for (int j_ = 0; j_ < 8; ++j_) { pb0_[j_] = f2bf(B[j_]); pb1_[j_] = f2bf(B[8 + j_]); } \
    *(short8*)(&As[buf][tid * 8])        = A0; \
    *(short8*)(&As[buf][2048 + tid * 8]) = A1; \
    *(short8*)(&Bs[buf][tid * 8])        = pb0_; \
    *(short8*)(&Bs[buf][2048 + tid * 8]) = pb1_; \
  } while (0)

  {
    short8 a00, a01, a10, a11;
    float rb0[16], rb1[16];
    F2_LOAD(0, a00, a01, rb0);
    F2_DSW(0, a00, a01, rb0);
    F2_LOAD(1, a10, a11, rb1);
    LGKM0(); SBAR();
    for (int kc = 0; kc < 30; kc += 2) {
      F2_LOAD(kc + 2, a00, a01, rb0);
      STG_COMP(0);
      F2_DSW(1, a10, a11, rb1);
      LGKM0(); SBAR();
      F2_LOAD(kc + 3, a10, a11, rb1);
      STG_COMP(1);
      F2_DSW(0, a00, a01, rb0);
      LGKM0(); SBAR();
    }
    STG_COMP(0);
    F2_DSW(1, a10, a11, rb1);
    LGKM0(); SBAR();
    STG_COMP(1);
  }

  const float* b2e = b2 + e * EMBED;
#pragma unroll
  for (int i = 0; i < 4; ++i) {
    int rl = wm * 64 + i * 16 + quad * 4;
#pragma unroll
    for (int rg = 0; rg < 4; ++rg) {
      int pos = mt * 128 + rl + rg;
      if (pos < cnt) {
        int r = base_e + pos;
        int tok = row_token[r];
        float wgt = row_w[r];
        float* orow = out + (size_t)tok * EMBED;
#pragma unroll
        for (int j = 0; j < 4; ++j) {
          int col = n0 + wn * 64 + j * 16 + l15;
          float v = acc[i][j][rg] + (sp == 0 ? b2e[col] : 0.f);
          atomicAdd(orow + col, v * wgt);
        }
      }
    }
  }
}

extern "C" void kernel_launch(void* const* d_in, const int* in_sizes, int n_in,
                              void* d_out, int out_size, void* d_ws, size_t ws_size,
                              hipStream_t stream) {
  (void)n_in; (void)ws_size;
  const float* x   = (const float*)d_in[0];
  const float* gw  = (const float*)d_in[1];
  const float* w1  = (const float*)d_in[2];
  const float* b1  = (const float*)d_in[3];
  const float* w2  = (const float*)d_in[4];
  const float* b2  = (const float*)d_in[5];
  float* out = (float*)d_out;
  int T = in_sizes[0] / EMBED;  // 1024

  char* w = (char*)d_ws;
  int*    count     = (int*)(w + WS_COUNT);
  int*    base      = (int*)(w + WS_BASE);
  int2*   t_idx     = (int2*)(w + WS_TIDX);
  float2* t_w       = (float2*)(w + WS_TW);
  int*    row_token = (int*)(w + WS_ROWTOK);
  float*  row_w     = (float*)(w + WS_ROWW);
  unsigned short* H = (unsigned short*)(w + WS_H);

  hipMemsetAsync(count, 0, 32, stream);
  hipMemsetAsync(out, 0, (size_t)out_size * sizeof(float), stream);
  router_kernel<<<T / 4, 256, 0, stream>>>(x, gw, count, t_idx, t_w);
  assign_kernel<<<1, 256, 0, stream>>>(count, base, t_idx, t_w, row_token, row_w, T);
  ffn1_kernel<<<dim3(HIDDEN / 128, 64), 256, 0, stream>>>(x, w1, b1, count, base, row_token, H);
  ffn2_kernel<<<dim3(EMBED / 128, 64, 4), 256, 0, stream>>>(H, w2, b2, count, base, row_token, row_w, out);
}